// Round 3
// baseline (15565.598 us; speedup 1.0000x reference)
//
#include <hip/hip_runtime.h>
#include <hip/hip_bf16.h>
#include <hip/hip_fp16.h>

// ---------------------------------------------------------------------------
// 4-layer LSTM (H=1024, B=64, T=256) + FC, persistent pipelined kernel.
// R3: 512 threads/WG (8 waves -> 2x outstanding sc-load streams), single-stage
//     f32 ds_add_f32 reduce (fewer barriers, full precision).
// - 256 WGs (1 per CU), 4 layer-groups x 64 WGs, dataflow flag sync
// - per WG: 64 gate rows (16 hidden units); w_hh slice LDS-resident (fp16 frags)
// - w_ih folded into K=2048 matmul, streamed frag-packed from L2 (plain loads)
// - ALL cross-WG traffic (h ring + flags) via agent-scope RELAXED atomics
//   (sc-coherence bits; __syncthreads drains vmcnt before tid0 signals)
// ---------------------------------------------------------------------------

#define H      1024
#define BATCH  64
#define T      256
#define RINGN  8

typedef _Float16 f16x8 __attribute__((ext_vector_type(8)));
typedef _Float16 f16x4 __attribute__((ext_vector_type(4)));
typedef float    f32x4 __attribute__((ext_vector_type(4)));

// ws layout (bytes)
#define WPACK_HH_OFF 0ull
#define WPACK_HH_SZ  (4ull*64*32*4*64*8*2)           // 33554432: [l][wg][ks][nt][lane][8] f16
#define WPACK_IH_OFF (WPACK_HH_OFF + WPACK_HH_SZ)
#define WPACK_IH_SZ  (3ull*64*32*4*64*8*2)           // 25165824
#define HRING_OFF    (WPACK_IH_OFF + WPACK_IH_SZ)
#define HRING_SZ     (4ull*RINGN*BATCH*H*2)          // 4194304: [l][slot][b][j] f16
#define CNT_OFF      (HRING_OFF + HRING_SZ)
#define CNT_SZ       (4ull*257*16*4)                 // produced flags, 64B-padded entries
#define CNT2_OFF     (CNT_OFF + CNT_SZ)
#define CNT2_SZ      CNT_SZ                          // consumed flags (ring backpressure)
#define WS_NEEDED    (CNT2_OFF + CNT2_SZ)

__device__ __forceinline__ int cidx(int l, int s) { return (l*257 + s)*16; }

__device__ __forceinline__ void wait_eq64(int* p) {
  int it = 0;
  while (__hip_atomic_load(p, __ATOMIC_RELAXED, __HIP_MEMORY_SCOPE_AGENT) < 64) {
    __builtin_amdgcn_s_sleep(1);
    if (++it > 100000000) break;   // failsafe: never hang the harness
  }
}

__device__ __forceinline__ f16x8 load_h8(const _Float16* p) {
  const unsigned long long* q = (const unsigned long long*)p;
  unsigned long long lo = __hip_atomic_load(q,     __ATOMIC_RELAXED, __HIP_MEMORY_SCOPE_AGENT);
  unsigned long long hi = __hip_atomic_load(q + 1, __ATOMIC_RELAXED, __HIP_MEMORY_SCOPE_AGENT);
  union { unsigned long long u[2]; f16x8 v; } c;
  c.u[0] = lo; c.u[1] = hi;
  return c.v;
}

// --- pack weights fp32 -> fp16 MFMA-fragment layout; zero h ring slot 0; preset cnt[l][0]=64
__global__ void pack_kernel(const float* __restrict__ w_ih_rest,
                            const float* __restrict__ w_hh,
                            char* __restrict__ ws)
{
  const long long NS_HH = 4ll*64*32*4*64;   // 2097152
  const long long NS_IH = 3ll*64*32*4*64;   // 1572864
  const long long NS_HZ = 4ll*8192;         // uint4 slots to zero slot-0 of each layer ring
  const long long NTOT  = NS_HH + NS_IH + NS_HZ + 4;
  _Float16* whh_dst = (_Float16*)(ws + WPACK_HH_OFF);
  _Float16* wih_dst = (_Float16*)(ws + WPACK_IH_OFF);
  for (long long i = blockIdx.x*(long long)blockDim.x + threadIdx.x; i < NTOT;
       i += (long long)gridDim.x*blockDim.x) {
    if (i < NS_HH + NS_IH) {
      const bool is_hh = (i < NS_HH);
      long long slot = is_hh ? i : (i - NS_HH);
      long long j = slot;
      int lane = (int)(j & 63); j >>= 6;
      int nt   = (int)(j & 3);  j >>= 2;
      int ks   = (int)(j & 31); j >>= 5;
      int wg   = (int)(j & 63); j >>= 6;
      int l    = (int)j;
      int row = nt*1024 + wg*16 + (lane & 15);      // global gate row (nt = gate: i,f,g,o)
      int col = ks*32 + (lane >> 4)*8;
      const float* src = (is_hh ? w_hh : w_ih_rest) + ((long long)l*4096 + row)*1024 + col;
      f16x8 v;
      #pragma unroll
      for (int e = 0; e < 8; e++) v[e] = (_Float16)src[e];
      *(f16x8*)((is_hh ? whh_dst : wih_dst) + slot*8) = v;
    } else if (i < NS_HH + NS_IH + NS_HZ) {
      long long j = i - (NS_HH + NS_IH);
      long long l = j >> 13;            // /8192
      long long off = j & 8191;
      uint4 z = make_uint4(0,0,0,0);
      ((uint4*)(ws + HRING_OFF))[(l*RINGN)*8192 + off] = z;   // zero h[l][slot0]
    } else {
      int l = (int)(i - (NS_HH + NS_IH + NS_HZ));
      ((int*)(ws + CNT_OFF))[cidx(l,0)] = 64;                 // initial state "produced"
    }
  }
}

__global__ __launch_bounds__(512, 1) void lstm_main(
    const float* __restrict__ x,
    const float* __restrict__ wih0,
    const float* __restrict__ bih,
    const float* __restrict__ bhh,
    char* __restrict__ ws)
{
  extern __shared__ char lds[];
  _Float16* whh_lds = (_Float16*)lds;              // 131072 B, frag layout [ks][nt][lane][8]
  float*    gbuf    = (float*)(lds + 131072);      // 16384 B: gates f32 [frag16][reg4][lane64]

  const int l   = blockIdx.x >> 6;
  const int wg  = blockIdx.x & 63;
  const int tid = threadIdx.x;
  const int wave = tid >> 6;
  const int lane = tid & 63;

  const _Float16* wpack_hh = (const _Float16*)(ws + WPACK_HH_OFF) + (size_t)(l*64 + wg)*65536;
  const _Float16* wpack_ih = (l > 0)
      ? (const _Float16*)(ws + WPACK_IH_OFF) + (size_t)((l-1)*64 + wg)*65536
      : wpack_hh;  // unused for l==0
  _Float16* hring = (_Float16*)(ws + HRING_OFF);
  int* cnt  = (int*)(ws + CNT_OFF);
  int* cnt2 = (int*)(ws + CNT2_OFF);

  // stage w_hh slice into LDS (one-time; wpack is immutable during this kernel)
  {
    const uint4* src = (const uint4*)wpack_hh;
    uint4* dst = (uint4*)whh_lds;
    for (int i = tid; i < 8192; i += 512) dst[i] = src[i];
  }
  // zero the f32 gate accumulation buffer
  for (int i = tid; i < 4096; i += 512) gbuf[i] = 0.f;

  // elementwise ownership: thread -> (batch b_ew, 2 hidden units u0..u0+1)
  const int b_ew = tid >> 3;
  const int u0   = (tid & 7) * 2;
  float cst[2] = {0.f, 0.f};
  float bias[2][4];            // [item][gate]
  float wx0[2][4], wx1[2][4];  // layer-0 input weights (K=2 handled in VALU)
  #pragma unroll
  for (int ii = 0; ii < 2; ii++) {
    #pragma unroll
    for (int g = 0; g < 4; g++) {
      int row = g*1024 + wg*16 + u0 + ii;
      bias[ii][g] = bih[l*4096 + row] + bhh[l*4096 + row];
      if (l == 0) { wx0[ii][g] = wih0[row*2]; wx1[ii][g] = wih0[row*2 + 1]; }
      else        { wx0[ii][g] = 0.f;         wx1[ii][g] = 0.f; }
    }
  }
  __syncthreads();

  const int m_row = lane & 15, quad = lane >> 4;

  for (int s = 1; s <= T; s++) {
    // three wait conditions handled by three different waves (parallel spins)
    if (tid == 0)          wait_eq64(&cnt[cidx(l, s-1)]);          // group lockstep + own h
    else if (tid == 64)  { if (l > 0) wait_eq64(&cnt[cidx(l-1, s)]); }          // input from below
    else if (tid == 128) { if (l < 3 && s > RINGN) wait_eq64(&cnt2[cidx(l, s-RINGN)]); } // ring bp
    __syncthreads();   // barrier 1: flags seen + gbuf zeroed

    // A source: for l>0 waves 0-3 consume h_below[s] (with w_ih), waves 4-7 h_own[s-1] (w_hh)
    const _Float16* asrc = (l > 0 && wave < 4)
        ? hring + ((size_t)(l-1)*RINGN + (s & 7))*65536
        : hring + ((size_t)l*RINGN + ((s-1) & 7))*65536;

    f32x4 acc[4][4];
    #pragma unroll
    for (int mt = 0; mt < 4; mt++)
      #pragma unroll
      for (int nt = 0; nt < 4; nt++) acc[mt][nt] = (f32x4){0.f, 0.f, 0.f, 0.f};

    auto kbody = [&](int ks, bool from_lds) {
      const int kb = ks*32 + quad*8;
      f16x8 a[4], bb[4];
      #pragma unroll
      for (int mt = 0; mt < 4; mt++)
        a[mt] = load_h8(asrc + (size_t)(mt*16 + m_row)*1024 + kb);
      if (from_lds) {
        #pragma unroll
        for (int nt = 0; nt < 4; nt++)
          bb[nt] = *(const f16x8*)(whh_lds + ((ks*4 + nt)*64 + lane)*8);
      } else {
        #pragma unroll
        for (int nt = 0; nt < 4; nt++)
          bb[nt] = *(const f16x8*)(wpack_ih + ((size_t)(ks*4 + nt)*64 + lane)*8);
      }
      #pragma unroll
      for (int mt = 0; mt < 4; mt++)
        #pragma unroll
        for (int nt = 0; nt < 4; nt++)
          acc[mt][nt] = __builtin_amdgcn_mfma_f32_16x16x32_f16(a[mt], bb[nt], acc[mt][nt], 0, 0, 0);
    };

    if (l == 0) {
      #pragma unroll 4
      for (int i = 0; i < 4; i++) kbody(wave*4 + i, true);          // K=1024 w_hh over 8 waves
    } else if (wave < 4) {
      #pragma unroll 4
      for (int i = 0; i < 8; i++) kbody(wave*8 + i, false);         // w_ih quarter (L2 stream)
    } else {
      #pragma unroll 4
      for (int i = 0; i < 8; i++) kbody((wave-4)*8 + i, true);      // w_hh quarter (LDS)
    }

    // single-stage f32 reduce: every wave ds_add's its partial frags
    // layout gbuf[((f*4+reg)*64 + lane)] -> per-instruction stride-1 (conflict-free)
    #pragma unroll
    for (int mt = 0; mt < 4; mt++)
      #pragma unroll
      for (int nt = 0; nt < 4; nt++)
        #pragma unroll
        for (int e = 0; e < 4; e++)
          atomicAdd(&gbuf[((mt*4 + nt)*4 + e)*64 + lane], acc[mt][nt][e]);

    __syncthreads();   // barrier 2: reduce done; also all A-reads retired
    if (tid == 0 && l > 0)
      __hip_atomic_fetch_add(&cnt2[cidx(l-1, s)], 1, __ATOMIC_RELAXED, __HIP_MEMORY_SCOPE_AGENT);

    // elementwise gates -> c,h  (fp32)
    {
      const int mt = b_ew >> 4, q = (b_ew & 15) >> 2, reg = b_ew & 3;
      float xs0 = 0.f, xs1 = 0.f;
      if (l == 0) {
        xs0 = x[((size_t)b_ew*T + (s-1))*2];
        xs1 = x[((size_t)b_ew*T + (s-1))*2 + 1];
      }
      union { _Float16 h[2]; unsigned u; } hv;
      #pragma unroll
      for (int ii = 0; ii < 2; ii++) {
        const int u = u0 + ii;
        float pre[4];
        #pragma unroll
        for (int g = 0; g < 4; g++)
          pre[g] = gbuf[((mt*4 + g)*4 + reg)*64 + (u + 16*q)] + bias[ii][g]
                 + wx0[ii][g]*xs0 + wx1[ii][g]*xs1;
        float ig = 1.f/(1.f + __expf(-pre[0]));
        float fg = 1.f/(1.f + __expf(-pre[1]));
        float gg = 2.f/(1.f + __expf(-2.f*pre[2])) - 1.f;
        float og = 1.f/(1.f + __expf(-pre[3]));
        float c  = fg*cst[ii] + ig*gg;
        cst[ii] = c;
        float th = 2.f/(1.f + __expf(-2.f*c)) - 1.f;
        hv.h[ii] = (_Float16)(og*th);
      }
      _Float16* hdst = hring + ((size_t)l*RINGN + (s & 7))*65536 + (size_t)b_ew*1024 + wg*16 + u0;
      __hip_atomic_store((unsigned*)hdst, hv.u, __ATOMIC_RELAXED, __HIP_MEMORY_SCOPE_AGENT);
    }
    __syncthreads();   // barrier 3: gbuf reads done + h stores drained (vmcnt)
    if (tid == 0)
      __hip_atomic_fetch_add(&cnt[cidx(l, s)], 1, __ATOMIC_RELAXED, __HIP_MEMORY_SCOPE_AGENT);
    // re-zero gbuf for next step (next use is after barrier 1 of step s+1)
    for (int i = tid; i < 4096; i += 512) gbuf[i] = 0.f;
  }
}

__global__ void fc_kernel(const char* __restrict__ ws,
                          const float* __restrict__ fcw,
                          const float* __restrict__ fcb,
                          float* __restrict__ out)
{
  const _Float16* h3 = (const _Float16*)(ws + HRING_OFF)
                     + ((size_t)3*RINGN + (T & 7))*65536;   // layer 3, slot of t=256
  __shared__ float red[256];
  const int tid = threadIdx.x;
  const int b = tid >> 2, p = tid & 3;
  float sum = 0.f;
  for (int j = p*256; j < p*256 + 256; j++)
    sum += fcw[j] * (float)h3[(size_t)b*1024 + j];
  red[tid] = sum;
  __syncthreads();
  if (p == 0)
    out[b] = red[tid] + red[tid+1] + red[tid+2] + red[tid+3] + fcb[0];
}

extern "C" void kernel_launch(void* const* d_in, const int* in_sizes, int n_in,
                              void* d_out, int out_size, void* d_ws, size_t ws_size,
                              hipStream_t stream)
{
  const float* x    = (const float*)d_in[0];
  const float* wih0 = (const float*)d_in[1];
  const float* wihr = (const float*)d_in[2];
  const float* whh  = (const float*)d_in[3];
  const float* bih  = (const float*)d_in[4];
  const float* bhh  = (const float*)d_in[5];
  const float* fcw  = (const float*)d_in[6];
  const float* fcb  = (const float*)d_in[7];
  float* out = (float*)d_out;
  char* ws = (char*)d_ws;
  (void)in_sizes; (void)n_in; (void)out_size;
  if (ws_size < WS_NEEDED) return;   // need ~63 MB scratch

  // opt-in to 147456 B dynamic LDS (host-side, idempotent, capture-safe)
  hipFuncSetAttribute(reinterpret_cast<const void*>(lstm_main),
                      hipFuncAttributeMaxDynamicSharedMemorySize, 147456);

  hipMemsetAsync(ws + CNT_OFF, 0, (size_t)(CNT_SZ + CNT2_SZ), stream);
  pack_kernel<<<512, 256, 0, stream>>>(wihr, whh, ws);
  lstm_main<<<256, 512, 147456, stream>>>(x, wih0, bih, bhh, ws);
  fc_kernel<<<1, 256, 0, stream>>>(ws, fcw, fcb, out);
}

// Round 4
// 4102.573 us; speedup vs baseline: 3.7941x; 3.7941x over previous
//
#include <hip/hip_runtime.h>
#include <hip/hip_bf16.h>
#include <hip/hip_fp16.h>

// ---------------------------------------------------------------------------
// 4-layer LSTM (H=1024, B=64, T=256) + FC, persistent pipelined kernel.
// R4: revert to proven R2 structure (256 thr, 4 waves, f16 two-stage reduce).
//     ONE change: consumers read h via PLAIN cached loads from a fresh-address
//     (bit-reversed slot) ring -> h flows through per-XCD L2 (34.5 TB/s)
//     instead of 64 MB/step of sc loads through the IF$ fabric.
//     Producers still sc write-through (IF$ = source of truth). A one-time
//     agent-acquire fence (buffer_inv sc1) at kernel start invalidates stale
//     L1/L2 lines from prior replays; within a replay ring addresses are
//     write-once-then-read => no stale line can exist. Falls back to the R2
//     sc-load modular-ring path if ws_size < ~194 MB.
// ---------------------------------------------------------------------------

#define H      1024
#define BATCH  64
#define T      256
#define RINGN  8

typedef _Float16 f16x8 __attribute__((ext_vector_type(8)));
typedef _Float16 f16x4 __attribute__((ext_vector_type(4)));
typedef float    f32x4 __attribute__((ext_vector_type(4)));

// ws layout (bytes)
#define WPACK_HH_SZ  (4ull*64*32*4*64*8*2)           // 33554432: [l][wg][ks][nt][lane][8] f16
#define WPACK_IH_SZ  (3ull*64*32*4*64*8*2)           // 25165824
#define HRING_OFF    (WPACK_HH_SZ + WPACK_IH_SZ)     // 58720256
#define SLOT_ELEMS   65536                           // per (l,slot): 64 batch x 1024 units f16
#define SLOT_BYTES   131072ull
#define CNT_INTS     (4*257*16)                      // flags, 64B-padded entries
#define CNT_BYTES    ((unsigned long long)CNT_INTS*4)

__host__ __device__ __forceinline__ unsigned long long ring_bytes(int nslot) {
  return 4ull*(unsigned)nslot*SLOT_BYTES;
}
__device__ __forceinline__ int cidx(int l, int s) { return (l*257 + s)*16; }

// fresh mode: bit-reversed slot index kills any sequential-prefetch adjacency
__device__ __forceinline__ int aslot(int s, int fresh) {
  if (!fresh) return s & 7;
  return (s >= 256) ? 256 : (int)(__brev((unsigned)s) >> 24);
}

__device__ __forceinline__ void wait_eq64(int* p) {
  int it = 0;
  while (__hip_atomic_load(p, __ATOMIC_RELAXED, __HIP_MEMORY_SCOPE_AGENT) < 64) {
    __builtin_amdgcn_s_sleep(1);
    if (++it > 100000000) break;   // failsafe: never hang the harness
  }
}

__device__ __forceinline__ f16x8 load_h8_sc(const _Float16* p) {
  const unsigned long long* q = (const unsigned long long*)p;
  unsigned long long lo = __hip_atomic_load(q,     __ATOMIC_RELAXED, __HIP_MEMORY_SCOPE_AGENT);
  unsigned long long hi = __hip_atomic_load(q + 1, __ATOMIC_RELAXED, __HIP_MEMORY_SCOPE_AGENT);
  union { unsigned long long u[2]; f16x8 v; } c;
  c.u[0] = lo; c.u[1] = hi;
  return c.v;
}

// --- pack weights fp32 -> fp16 MFMA-fragment layout; zero h ring slot 0; preset cnt[l][0]=64
__global__ void pack_kernel(const float* __restrict__ w_ih_rest,
                            const float* __restrict__ w_hh,
                            char* __restrict__ ws, int nslot)
{
  const long long NS_HH = 4ll*64*32*4*64;   // 2097152
  const long long NS_IH = 3ll*64*32*4*64;   // 1572864
  const long long NS_HZ = 4ll*8192;         // uint4 slots to zero slot-0 of each layer ring
  const long long NTOT  = NS_HH + NS_IH + NS_HZ + 4;
  _Float16* whh_dst = (_Float16*)ws;
  _Float16* wih_dst = (_Float16*)(ws + WPACK_HH_SZ);
  int* cnt = (int*)(ws + HRING_OFF + ring_bytes(nslot));
  for (long long i = blockIdx.x*(long long)blockDim.x + threadIdx.x; i < NTOT;
       i += (long long)gridDim.x*blockDim.x) {
    if (i < NS_HH + NS_IH) {
      const bool is_hh = (i < NS_HH);
      long long slot = is_hh ? i : (i - NS_HH);
      long long j = slot;
      int lane = (int)(j & 63); j >>= 6;
      int nt   = (int)(j & 3);  j >>= 2;
      int ks   = (int)(j & 31); j >>= 5;
      int wg   = (int)(j & 63); j >>= 6;
      int l    = (int)j;
      int row = nt*1024 + wg*16 + (lane & 15);      // global gate row (nt = gate: i,f,g,o)
      int col = ks*32 + (lane >> 4)*8;
      const float* src = (is_hh ? w_hh : w_ih_rest) + ((long long)l*4096 + row)*1024 + col;
      f16x8 v;
      #pragma unroll
      for (int e = 0; e < 8; e++) v[e] = (_Float16)src[e];
      *(f16x8*)((is_hh ? whh_dst : wih_dst) + slot*8) = v;
    } else if (i < NS_HH + NS_IH + NS_HZ) {
      long long j = i - (NS_HH + NS_IH);
      long long l = j >> 13;            // /8192
      long long off = j & 8191;
      uint4 z = make_uint4(0,0,0,0);
      ((uint4*)(ws + HRING_OFF))[(l*(long long)nslot)*8192 + off] = z;  // zero h[l][slot0]
    } else {
      int l = (int)(i - (NS_HH + NS_IH + NS_HZ));
      cnt[cidx(l,0)] = 64;                                  // initial state "produced"
    }
  }
}

__global__ __launch_bounds__(256, 1) void lstm_main(
    const float* __restrict__ x,
    const float* __restrict__ wih0,
    const float* __restrict__ bih,
    const float* __restrict__ bhh,
    char* __restrict__ ws, int nslot, int fresh)
{
  // one-time agent acquire: emits buffer_inv sc1 -> kills stale L1/L2 lines
  // from previous graph replays / poison-memset. Required for fresh-mode
  // plain consumer loads; harmless otherwise.
  __builtin_amdgcn_fence(__ATOMIC_ACQUIRE, "agent");

  extern __shared__ char lds[];
  _Float16* whh_lds = (_Float16*)lds;              // 131072 B, frag layout [ks][nt][lane][8]
  _Float16* buf0    = (_Float16*)(lds + 131072);   // 8192 B partial-sum frags (waves 0+2)
  _Float16* buf1    = (_Float16*)(lds + 139264);   // 8192 B partial-sum frags (waves 1+3)

  const int l   = blockIdx.x >> 6;
  const int wg  = blockIdx.x & 63;
  const int tid = threadIdx.x;
  const int wave = tid >> 6;
  const int lane = tid & 63;

  const _Float16* wpack_hh = (const _Float16*)ws + (size_t)(l*64 + wg)*65536;
  const _Float16* wpack_ih = (l > 0)
      ? (const _Float16*)(ws + WPACK_HH_SZ) + (size_t)((l-1)*64 + wg)*65536
      : wpack_hh;  // unused for l==0
  _Float16* hring = (_Float16*)(ws + HRING_OFF);
  int* cnt  = (int*)(ws + HRING_OFF + ring_bytes(nslot));
  int* cnt2 = cnt + CNT_INTS;

  // stage w_hh slice into LDS (one-time; wpack is immutable during this kernel)
  {
    const uint4* src = (const uint4*)wpack_hh;
    uint4* dst = (uint4*)whh_lds;
    for (int i = tid; i < 8192; i += 256) dst[i] = src[i];
  }

  // elementwise ownership: thread -> (batch b_ew, 4 consecutive hidden units u0..u0+3)
  const int b_ew = tid >> 2;
  const int u0   = (tid & 3) * 4;
  float cst[4] = {0.f, 0.f, 0.f, 0.f};
  float bias[4][4];            // [item][gate]
  float wx0[4][4], wx1[4][4];  // layer-0 input weights (K=2 handled in VALU)
  #pragma unroll
  for (int ii = 0; ii < 4; ii++) {
    #pragma unroll
    for (int g = 0; g < 4; g++) {
      int row = g*1024 + wg*16 + u0 + ii;
      bias[ii][g] = bih[l*4096 + row] + bhh[l*4096 + row];
      if (l == 0) { wx0[ii][g] = wih0[row*2]; wx1[ii][g] = wih0[row*2 + 1]; }
      else        { wx0[ii][g] = 0.f;         wx1[ii][g] = 0.f; }
    }
  }
  __syncthreads();

  const int m_row = lane & 15, quad = lane >> 4;

  for (int s = 1; s <= T; s++) {
    // wait conditions on different waves (parallel spins)
    if (tid == 0)          wait_eq64(&cnt[cidx(l, s-1)]);          // group lockstep + own h
    else if (tid == 64)  { if (l > 0) wait_eq64(&cnt[cidx(l-1, s)]); }          // input from below
    else if (tid == 128) { if (!fresh && l < 3 && s > RINGN) wait_eq64(&cnt2[cidx(l, s-RINGN)]); }
    __syncthreads();

    // A source: for l>0 waves 0-1 consume h_below[s] (with w_ih), waves 2-3 h_own[s-1] (w_hh)
    const _Float16* asrc = (l > 0 && wave < 2)
        ? hring + ((size_t)(l-1)*nslot + aslot(s,   fresh))*SLOT_ELEMS
        : hring + ((size_t)l*nslot     + aslot(s-1, fresh))*SLOT_ELEMS;

    f32x4 acc[4][4];
    #pragma unroll
    for (int mt = 0; mt < 4; mt++)
      #pragma unroll
      for (int nt = 0; nt < 4; nt++) acc[mt][nt] = (f32x4){0.f, 0.f, 0.f, 0.f};

    auto kbody = [&](int ks, bool from_lds, bool plain) {
      const int kb = ks*32 + quad*8;
      f16x8 a[4], bb[4];
      #pragma unroll
      for (int mt = 0; mt < 4; mt++) {
        const _Float16* ap = asrc + (size_t)(mt*16 + m_row)*1024 + kb;
        a[mt] = plain ? *(const f16x8*)ap : load_h8_sc(ap);
      }
      if (from_lds) {
        #pragma unroll
        for (int nt = 0; nt < 4; nt++)
          bb[nt] = *(const f16x8*)(whh_lds + ((ks*4 + nt)*64 + lane)*8);
      } else {
        #pragma unroll
        for (int nt = 0; nt < 4; nt++)
          bb[nt] = *(const f16x8*)(wpack_ih + ((size_t)(ks*4 + nt)*64 + lane)*8);
      }
      #pragma unroll
      for (int mt = 0; mt < 4; mt++)
        #pragma unroll
        for (int nt = 0; nt < 4; nt++)
          acc[mt][nt] = __builtin_amdgcn_mfma_f32_16x16x32_f16(a[mt], bb[nt], acc[mt][nt], 0, 0, 0);
    };

    if (fresh) {
      if (l == 0) {
        #pragma unroll 2
        for (int i = 0; i < 8; i++) kbody(wave*8 + i, true, true);
      } else if (wave < 2) {
        #pragma unroll 2
        for (int i = 0; i < 16; i++) kbody(wave*16 + i, false, true);
      } else {
        #pragma unroll 2
        for (int i = 0; i < 16; i++) kbody((wave-2)*16 + i, true, true);
      }
    } else {
      if (l == 0) {
        #pragma unroll 2
        for (int i = 0; i < 8; i++) kbody(wave*8 + i, true, false);
      } else if (wave < 2) {
        #pragma unroll 2
        for (int i = 0; i < 16; i++) kbody(wave*16 + i, false, false);
      } else {
        #pragma unroll 2
        for (int i = 0; i < 16; i++) kbody((wave-2)*16 + i, true, false);
      }
    }

    // combine 4 wave-partials -> buf0 (w0+w2), buf1 (w1+w3), fp16 frags
    _Float16* mybuf = ((wave & 1) == 0) ? buf0 : buf1;
    if (wave >= 2) {
      #pragma unroll
      for (int mt = 0; mt < 4; mt++)
        #pragma unroll
        for (int nt = 0; nt < 4; nt++) {
          f16x4 v;
          #pragma unroll
          for (int e = 0; e < 4; e++) v[e] = (_Float16)acc[mt][nt][e];
          *(f16x4*)(mybuf + ((mt*4 + nt)*64 + lane)*4) = v;
        }
    }
    __syncthreads();   // drains vmcnt: all h reads physically complete
    if (wave < 2) {
      #pragma unroll
      for (int mt = 0; mt < 4; mt++)
        #pragma unroll
        for (int nt = 0; nt < 4; nt++) {
          f16x4 p = *(f16x4*)(mybuf + ((mt*4 + nt)*64 + lane)*4);
          f16x4 v;
          #pragma unroll
          for (int e = 0; e < 4; e++) v[e] = (_Float16)(acc[mt][nt][e] + (float)p[e]);
          *(f16x4*)(mybuf + ((mt*4 + nt)*64 + lane)*4) = v;
        }
    }
    // ring backpressure signal only needed when slots are reused (fallback mode)
    if (!fresh && tid == 0 && l > 0)
      __hip_atomic_fetch_add(&cnt2[cidx(l-1, s)], 1, __ATOMIC_RELAXED, __HIP_MEMORY_SCOPE_AGENT);
    __syncthreads();

    // elementwise gates -> c,h  (fp32)
    {
      const int mt = b_ew >> 4, q = (b_ew & 15) >> 2, reg = b_ew & 3;
      float xs0 = 0.f, xs1 = 0.f;
      if (l == 0) {
        xs0 = x[((size_t)b_ew*T + (s-1))*2];
        xs1 = x[((size_t)b_ew*T + (s-1))*2 + 1];
      }
      f16x4 hv;
      #pragma unroll
      for (int ii = 0; ii < 4; ii++) {
        const int u = u0 + ii;
        float pre[4];
        #pragma unroll
        for (int g = 0; g < 4; g++) {
          int idx = ((mt*4 + g)*64 + (u + 16*q))*4 + reg;
          pre[g] = (float)buf0[idx] + (float)buf1[idx] + bias[ii][g]
                 + wx0[ii][g]*xs0 + wx1[ii][g]*xs1;
        }
        float ig = 1.f/(1.f + __expf(-pre[0]));
        float fg = 1.f/(1.f + __expf(-pre[1]));
        float gg = 2.f/(1.f + __expf(-2.f*pre[2])) - 1.f;
        float og = 1.f/(1.f + __expf(-pre[3]));
        float c  = fg*cst[ii] + ig*gg;
        cst[ii] = c;
        float th = 2.f/(1.f + __expf(-2.f*c)) - 1.f;
        hv[ii] = (_Float16)(og*th);
      }
      _Float16* hdst = hring + ((size_t)l*nslot + aslot(s, fresh))*SLOT_ELEMS
                     + (size_t)b_ew*1024 + wg*16 + u0;
      union { f16x4 v; unsigned long long u; } cv; cv.v = hv;
      // sc write-through: IF$ (coherence point) holds the authoritative copy
      __hip_atomic_store((unsigned long long*)hdst, cv.u,
                         __ATOMIC_RELAXED, __HIP_MEMORY_SCOPE_AGENT);
    }
    __syncthreads();   // drains vmcnt: h stores acked at coherence point before flag
    if (tid == 0)
      __hip_atomic_fetch_add(&cnt[cidx(l, s)], 1, __ATOMIC_RELAXED, __HIP_MEMORY_SCOPE_AGENT);
  }
}

__global__ void fc_kernel(const char* __restrict__ ws,
                          const float* __restrict__ fcw,
                          const float* __restrict__ fcb,
                          float* __restrict__ out, int nslot, int fresh)
{
  const _Float16* h3 = (const _Float16*)(ws + HRING_OFF)
                     + ((size_t)3*nslot + aslot(T, fresh))*SLOT_ELEMS;  // layer 3, t=256
  __shared__ float red[256];
  const int tid = threadIdx.x;
  const int b = tid >> 2, p = tid & 3;
  float sum = 0.f;
  for (int j = p*256; j < p*256 + 256; j++)
    sum += fcw[j] * (float)h3[(size_t)b*1024 + j];
  red[tid] = sum;
  __syncthreads();
  if (p == 0)
    out[b] = red[tid] + red[tid+1] + red[tid+2] + red[tid+3] + fcb[0];
}

extern "C" void kernel_launch(void* const* d_in, const int* in_sizes, int n_in,
                              void* d_out, int out_size, void* d_ws, size_t ws_size,
                              hipStream_t stream)
{
  const float* x    = (const float*)d_in[0];
  const float* wih0 = (const float*)d_in[1];
  const float* wihr = (const float*)d_in[2];
  const float* whh  = (const float*)d_in[3];
  const float* bih  = (const float*)d_in[4];
  const float* bhh  = (const float*)d_in[5];
  const float* fcw  = (const float*)d_in[6];
  const float* fcb  = (const float*)d_in[7];
  float* out = (float*)d_out;
  char* ws = (char*)d_ws;
  (void)in_sizes; (void)n_in; (void)out_size;

  const unsigned long long ws_big   = HRING_OFF + ring_bytes(257) + 2*CNT_BYTES; // ~193.6 MB
  const unsigned long long ws_small = HRING_OFF + ring_bytes(8)   + 2*CNT_BYTES; // ~63 MB
  if (ws_size < ws_small) return;
  const int fresh = (ws_size >= ws_big) ? 1 : 0;
  const int nslot = fresh ? 257 : 8;

  // opt-in to 147456 B dynamic LDS (host-side, idempotent, capture-safe)
  hipFuncSetAttribute(reinterpret_cast<const void*>(lstm_main),
                      hipFuncAttributeMaxDynamicSharedMemorySize, 147456);

  hipMemsetAsync(ws + HRING_OFF + ring_bytes(nslot), 0, (size_t)(2*CNT_BYTES), stream);
  pack_kernel<<<512, 256, 0, stream>>>(wihr, whh, ws, nslot);
  lstm_main<<<256, 256, 147456, stream>>>(x, wih0, bih, bhh, ws, nslot, fresh);
  fc_kernel<<<1, 256, 0, stream>>>(ws, fcw, fcb, out, nslot, fresh);
}